// Round 11
// baseline (339.787 us; speedup 1.0000x reference)
//
#include <hip/hip_runtime.h>
#include <hip/hip_bf16.h>

typedef __bf16 bf16_t;
typedef __bf16 bf16x4 __attribute__((ext_vector_type(4)));
typedef __bf16 bf16x8 __attribute__((ext_vector_type(8)));
typedef float f32x4 __attribute__((ext_vector_type(4)));

typedef const __attribute__((address_space(1))) void gvoid_t;
typedef __attribute__((address_space(3))) void lvoid_t;

#define MB (1UL<<20)
#define NEGINF (-__builtin_inff())
#define SCALE 0.08838834764831845f

__device__ __forceinline__ void gload_lds16(const void* g, void* l) {
    __builtin_amdgcn_global_load_lds((gvoid_t*)g, (lvoid_t*)l, 16, 0, 0);
}

// ---------------- merged cast f32 -> bf16: all 8 buffers in one launch --------
__global__ __launch_bounds__(256)
void cast8_kernel(const float* __restrict__ s0, bf16_t* __restrict__ d0,   // Wq 256K f4
                  const float* __restrict__ s1, bf16_t* __restrict__ d1,   // Wk
                  const float* __restrict__ s2, bf16_t* __restrict__ d2,   // Wv
                  const float* __restrict__ s3, bf16_t* __restrict__ d3,   // Wo
                  const float* __restrict__ s4, bf16_t* __restrict__ d4,   // We 512K
                  const float* __restrict__ s5, bf16_t* __restrict__ d5,   // Ws 512K
                  const float* __restrict__ s6, bf16_t* __restrict__ d6,   // in 1M
                  const float* __restrict__ s7, bf16_t* __restrict__ d7)   // mem 1M
{
    long i = (long)blockIdx.x * 256 + threadIdx.x;   // float4 index, total 4M
    const float* src; bf16_t* dst; long l;
    if      (i < 262144L)  { src = s0; dst = d0; l = i; }
    else if (i < 524288L)  { src = s1; dst = d1; l = i - 262144L; }
    else if (i < 786432L)  { src = s2; dst = d2; l = i - 524288L; }
    else if (i < 1048576L) { src = s3; dst = d3; l = i - 786432L; }
    else if (i < 1572864L) { src = s4; dst = d4; l = i - 1048576L; }
    else if (i < 2097152L) { src = s5; dst = d5; l = i - 1572864L; }
    else if (i < 3145728L) { src = s6; dst = d6; l = i - 2097152L; }
    else                   { src = s7; dst = d7; l = i - 3145728L; }
    float4 f = ((const float4*)src)[l];
    bf16x4 o;
    o[0] = (bf16_t)f.x; o[1] = (bf16_t)f.y; o[2] = (bf16_t)f.z; o[3] = (bf16_t)f.w;
    ((bf16x4*)dst)[l] = o;
}

// ---------------- generic BT GEMM: C[i,j] = sum_k A[i,k]*B[j,k] ----------------
// TM x 128 tile (TM=128: 4 waves 2x2 of 64x64; TM=64: 4 waves 1x4 of 64x32).
// BK=32, DEPTH-3 DMA pipeline: 3 LDS buffers, stage(t+2) issued each iter,
// counted vmcnt(2*LPS) => stage(t) landed while t+1,t+2 stay in flight.
// Hazards: buffer t%3 re-written by stage(t+3), issued after t's trailing
// barrier (all reads done). Branches block-uniform. Per-wave vmcnt covers
// each wave's own DMA portion; leading barrier makes whole tile visible.
template<int TM, int OUT_BF16, int HAS_BIAS, int RELU, int HAS_RES, int VT_OUT>
__global__ __launch_bounds__(256)
void gemm_bt(const bf16_t* __restrict__ Ap, int lda,
             const bf16_t* __restrict__ Bp, int ldb,
             const float* __restrict__ bias,
             const float* __restrict__ res, int ldres,
             void* __restrict__ Cp, int ldc,
             int K, int tilesN,
             long aOffB, long aOffH, long bOffB, long bOffH, long cOffZ, int nH)
{
    __shared__ bf16_t sA[3 * TM * 32];
    __shared__ bf16_t sB[3 * 128 * 32];

    const int z = blockIdx.y;
    const int zb = z / nH, zh = z % nH;
    Ap += zb * aOffB + zh * aOffH;
    Bp += zb * bOffB + zh * bOffH;
    const long cOff = (long)z * cOffZ;

    const int tile = blockIdx.x;
    const int tm = tile / tilesN, tn = tile % tilesN;
    const int rowBase = tm * TM, colBase = tn * 128;
    const int t = threadIdx.x;
    const int wave = t >> 6, lane = t & 63;
    const int wr = (TM == 128) ? ((wave >> 1) * 64) : 0;
    const int wc = (TM == 128) ? ((wave & 1) * 64) : (wave * 32);
    constexpr int NF = (TM == 128) ? 4 : 2;

    f32x4 acc[4][NF] = {};

    const int e0 = t * 8;
    const int srow = e0 >> 5, scol = e0 & 31;

    auto stage = [&](int tt, int bi) {
        const int k0 = tt * 32;
        #pragma unroll
        for (int r = 0; r < TM / 64; ++r) {
            const int row = r * 64 + srow;
            gload_lds16(Ap + (long)(rowBase + row) * lda + k0 + scol,
                        (char*)sA + bi * (TM * 64) + r * 4096 + wave * 1024);
        }
        #pragma unroll
        for (int r = 0; r < 2; ++r) {
            const int row = r * 64 + srow;
            gload_lds16(Bp + (long)(colBase + row) * ldb + k0 + scol,
                        (char*)sB + bi * 8192 + r * 4096 + wave * 1024);
        }
    };

    const int nt = K >> 5;
    stage(0, 0);
    stage(1, 1);

    const int kf = (lane >> 4) * 8;
    const int lr = lane & 15;

    for (int tt = 0; tt < nt; ++tt) {
        const int bi = tt % 3;
        if (tt + 2 < nt) {
            stage(tt + 2, (tt + 2) % 3);
            // stages tt+1, tt+2 stay in flight; stage(tt) guaranteed landed
            if constexpr (TM == 128) {
                asm volatile("s_waitcnt vmcnt(8)" ::: "memory");
            } else {
                asm volatile("s_waitcnt vmcnt(6)" ::: "memory");
            }
        } else if (tt + 1 < nt) {
            if constexpr (TM == 128) {
                asm volatile("s_waitcnt vmcnt(4)" ::: "memory");
            } else {
                asm volatile("s_waitcnt vmcnt(3)" ::: "memory");
            }
        } else {
            asm volatile("s_waitcnt vmcnt(0)" ::: "memory");
        }
        __builtin_amdgcn_s_barrier();

        bf16x8 af[4], bfr[NF];
        #pragma unroll
        for (int m = 0; m < 4; ++m)
            af[m] = *(const bf16x8*)&sA[bi * (TM * 32) + (wr + m * 16 + lr) * 32 + kf];
        #pragma unroll
        for (int n = 0; n < NF; ++n)
            bfr[n] = *(const bf16x8*)&sB[bi * 4096 + (wc + n * 16 + lr) * 32 + kf];
        #pragma unroll
        for (int m = 0; m < 4; ++m)
            #pragma unroll
            for (int n = 0; n < NF; ++n)
                acc[m][n] = __builtin_amdgcn_mfma_f32_16x16x32_bf16(af[m], bfr[n], acc[m][n], 0, 0, 0);

        __builtin_amdgcn_s_barrier();
    }

    #pragma unroll
    for (int m = 0; m < 4; ++m) {
        #pragma unroll
        for (int r = 0; r < 4; ++r) {
            const int i = rowBase + wr + m * 16 + (lane >> 4) * 4 + r;
            #pragma unroll
            for (int n = 0; n < NF; ++n) {
                const int j = colBase + wc + n * 16 + (lane & 15);
                float v = acc[m][n][r];
                if constexpr (HAS_BIAS) v += bias[j];
                if constexpr (RELU) v = fmaxf(v, 0.0f);
                if constexpr (HAS_RES) v += res[(long)i * ldres + j];
                if constexpr (VT_OUT) {
                    // V projection: write transposed per head: Vt[b][h][c][m]
                    const long o = (((long)(i >> 10) * 8 + (j >> 7)) * 128 + (j & 127)) * 1024 + (i & 1023);
                    ((bf16_t*)Cp)[o] = (bf16_t)v;
                } else if constexpr (OUT_BF16) {
                    ((bf16_t*)Cp)[cOff + (long)i * ldc + j] = (bf16_t)v;
                } else {
                    ((float*)Cp)[cOff + (long)i * ldc + j] = v;
                }
            }
        }
    }
}

// ---------------- gate + softmax: raw scores -> FINAL probs in place ----------
// One wave per row of 1024; row = (b*8+h)*1024 + n. All loads float4-coalesced.
__global__ __launch_bounds__(256)
void gate_softmax_kernel(float* __restrict__ Sio,           // (B,H,N,M) raw->probs
                         const float* __restrict__ factors, // (B,N,M)
                         const float* __restrict__ weights, // (B,M)
                         const int* __restrict__ mmask,     // (B,M)
                         const int* __restrict__ amask)     // (B,1,N,M)
{
    const int row = blockIdx.x * 4 + (threadIdx.x >> 6);
    const int lane = threadIdx.x & 63;
    const int n = row & 1023;
    const int b = row >> 13;
    float4* p = (float4*)(Sio + (long)row * 1024);
    const float4* fac = (const float4*)(factors + ((long)b * 1024 + n) * 1024);
    const float4* wt  = (const float4*)(weights + (long)b * 1024);
    const int4*   mm  = (const int4*)(mmask + (long)b * 1024);
    const int4*   am  = (const int4*)(amask + ((long)b * 1024 + n) * 1024);

    float vals[16];
    float mx = NEGINF;
    #pragma unroll
    for (int jj = 0; jj < 4; ++jj) {
        const int v4 = lane + jj * 64;
        float4 sc = p[v4];
        float4 fa = fac[v4];
        float4 w4 = wt[v4];
        int4 m4 = mm[v4];
        int4 a4 = am[v4];
        float4 g;
        g.x = (m4.x | a4.x) ? NEGINF : sc.x * SCALE * fa.x * w4.x;
        g.y = (m4.y | a4.y) ? NEGINF : sc.y * SCALE * fa.y * w4.y;
        g.z = (m4.z | a4.z) ? NEGINF : sc.z * SCALE * fa.z * w4.z;
        g.w = (m4.w | a4.w) ? NEGINF : sc.w * SCALE * fa.w * w4.w;
        vals[jj * 4 + 0] = g.x; vals[jj * 4 + 1] = g.y;
        vals[jj * 4 + 2] = g.z; vals[jj * 4 + 3] = g.w;
        mx = fmaxf(mx, fmaxf(fmaxf(g.x, g.y), fmaxf(g.z, g.w)));
    }
    #pragma unroll
    for (int off = 32; off > 0; off >>= 1) mx = fmaxf(mx, __shfl_xor(mx, off));
    float sum = 0.f;
    #pragma unroll
    for (int q = 0; q < 16; ++q) { float e = __expf(vals[q] - mx); vals[q] = e; sum += e; }
    #pragma unroll
    for (int off = 32; off > 0; off >>= 1) sum += __shfl_xor(sum, off);
    const float inv = 1.0f / sum;
    #pragma unroll
    for (int jj = 0; jj < 4; ++jj) {
        const int v4 = lane + jj * 64;
        float4 o;
        o.x = vals[jj * 4 + 0] * inv; o.y = vals[jj * 4 + 1] * inv;
        o.z = vals[jj * 4 + 2] * inv; o.w = vals[jj * 4 + 3] * inv;
        p[v4] = o;
    }
}

// ---------------- PV GEMM (64x128 tile, dbuf): hid = P @ Vt^T ----------------
// A-path: read prob strip (f32, coalesced), cvt bf16 -> LDS. Grid (16,32).
// Barrier: lgkmcnt(0) only (ds_writes). B-DMA for t+1 is implicitly drained by
// the prob-load register dependency (issued after the DMA, same vmcnt order)
// before procA(t+1) completes, so no vmcnt(0) drain is needed at the barrier.
__global__ __launch_bounds__(256)
void pv_kernel(const float* __restrict__ Sprob,       // (B,H,N,M) final probs
               const bf16_t* __restrict__ Vtb,        // [b][h][c][m]
               bf16_t* __restrict__ hidb)             // [b][n][h*128+c]
{
    __shared__ bf16_t sA[2 * 64 * 32];
    __shared__ bf16_t sB[2 * 128 * 32];

    const int bh = blockIdx.y;
    const int b = bh >> 3, h = bh & 7;
    const int rowBase = blockIdx.x * 64;
    const int t = threadIdx.x;
    const int wave = t >> 6, lane = t & 63;
    const int wc = wave * 32;

    const float* Sp = Sprob + (long)bh * 1048576;
    const bf16_t* Bp = Vtb + (long)bh * 131072;

    const int arow = rowBase + (t >> 2);       // 0..63 within tile
    const int acol = (t & 3) * 8;
    const float* Srow = Sp + (long)arow * 1024 + acol;

    f32x4 acc[4][2] = {};

    auto stageB = [&](int tt, int bi) {
        const int k0 = tt * 32;
        #pragma unroll
        for (int r = 0; r < 2; ++r) {
            const int row = r * 64 + ((t * 8) >> 5);
            gload_lds16(Bp + (long)row * 1024 + k0 + ((t * 8) & 31),
                        (char*)sB + bi * 8192 + r * 4096 + wave * 1024);
        }
    };

    auto procA = [&](int tt, int bi, float4 s0, float4 s1) {
        bf16x8 pb;
        pb[0] = (bf16_t)s0.x; pb[1] = (bf16_t)s0.y; pb[2] = (bf16_t)s0.z; pb[3] = (bf16_t)s0.w;
        pb[4] = (bf16_t)s1.x; pb[5] = (bf16_t)s1.y; pb[6] = (bf16_t)s1.z; pb[7] = (bf16_t)s1.w;
        *(bf16x8*)((char*)sA + bi * 4096 + t * 16) = pb;
    };

    // prologue: strip 0
    stageB(0, 0);
    {
        float4 s0 = *(const float4*)Srow;
        float4 s1 = *(const float4*)(Srow + 4);
        procA(0, 0, s0, s1);
    }
    asm volatile("s_waitcnt vmcnt(0) lgkmcnt(0)" ::: "memory");
    __builtin_amdgcn_s_barrier();

    const int kf = (lane >> 4) * 8;
    const int lr = lane & 15;

    for (int tt = 0; tt < 32; ++tt) {
        const int cur = tt & 1;
        float4 s0, s1;
        if (tt < 31) {
            stageB(tt + 1, cur ^ 1);
            s0 = *(const float4*)(Srow + (tt + 1) * 32);
            s1 = *(const float4*)(Srow + (tt + 1) * 32 + 4);
        }

        bf16x8 af[4], bfr[2];
        #pragma unroll
        for (int m = 0; m < 4; ++m)
            af[m] = *(const bf16x8*)&sA[cur * 2048 + (m * 16 + lr) * 32 + kf];
        #pragma unroll
        for (int n = 0; n < 2; ++n)
            bfr[n] = *(const bf16x8*)&sB[cur * 4096 + (wc + n * 16 + lr) * 32 + kf];
        #pragma unroll
        for (int m = 0; m < 4; ++m)
            #pragma unroll
            for (int n = 0; n < 2; ++n)
                acc[m][n] = __builtin_amdgcn_mfma_f32_16x16x32_bf16(af[m], bfr[n], acc[m][n], 0, 0, 0);

        if (tt < 31) procA(tt + 1, cur ^ 1, s0, s1);

        asm volatile("s_waitcnt lgkmcnt(0)" ::: "memory");
        __builtin_amdgcn_s_barrier();
    }

    #pragma unroll
    for (int m = 0; m < 4; ++m) {
        #pragma unroll
        for (int r = 0; r < 4; ++r) {
            const int i = rowBase + m * 16 + (lane >> 4) * 4 + r;
            #pragma unroll
            for (int n = 0; n < 2; ++n) {
                const int j = wc + n * 16 + (lane & 15);
                hidb[((long)b * 1024 + i) * 1024 + h * 128 + j] = (bf16_t)acc[m][n][r];
            }
        }
    }
}

// ---------------- LayerNorm over rows of 1024, one wave per row ----------------
template<int WRITE_BF16>
__global__ __launch_bounds__(256)
void ln_kernel(const float* __restrict__ x,
               const float* __restrict__ g,
               const float* __restrict__ bt,
               float* __restrict__ outf,
               bf16_t* __restrict__ outb)
{
    const int row = blockIdx.x * 4 + (threadIdx.x >> 6);
    const int lane = threadIdx.x & 63;
    const float* p = x + (long)row * 1024;
    float v[16];
    float s = 0.f;
    #pragma unroll
    for (int jj = 0; jj < 4; ++jj) {
        float4 f = ((const float4*)p)[lane + jj * 64];
        v[jj * 4 + 0] = f.x; v[jj * 4 + 1] = f.y; v[jj * 4 + 2] = f.z; v[jj * 4 + 3] = f.w;
        s += f.x + f.y + f.z + f.w;
    }
    #pragma unroll
    for (int off = 32; off > 0; off >>= 1) s += __shfl_xor(s, off);
    const float mu = s * (1.0f / 1024.0f);
    float q = 0.f;
    #pragma unroll
    for (int i = 0; i < 16; ++i) { float d = v[i] - mu; q += d * d; }
    #pragma unroll
    for (int off = 32; off > 0; off >>= 1) q += __shfl_xor(q, off);
    const float rstd = rsqrtf(q * (1.0f / 1024.0f) + 1e-5f);
    #pragma unroll
    for (int jj = 0; jj < 4; ++jj) {
        const int v4 = lane + jj * 64;
        float4 gg = ((const float4*)g)[v4];
        float4 bb = ((const float4*)bt)[v4];
        float4 o;
        o.x = (v[jj * 4 + 0] - mu) * rstd * gg.x + bb.x;
        o.y = (v[jj * 4 + 1] - mu) * rstd * gg.y + bb.y;
        o.z = (v[jj * 4 + 2] - mu) * rstd * gg.z + bb.z;
        o.w = (v[jj * 4 + 3] - mu) * rstd * gg.w + bb.w;
        ((float4*)outf)[(long)row * 256 + v4] = o;
        if constexpr (WRITE_BF16) {
            bf16x4 ob;
            ob[0] = (bf16_t)o.x; ob[1] = (bf16_t)o.y; ob[2] = (bf16_t)o.z; ob[3] = (bf16_t)o.w;
            ((bf16x4*)outb)[(long)row * 256 + v4] = ob;
        }
    }
}

extern "C" void kernel_launch(void* const* d_in, const int* in_sizes, int n_in,
                              void* d_out, int out_size, void* d_ws, size_t ws_size,
                              hipStream_t stream)
{
    (void)in_sizes; (void)n_in; (void)out_size; (void)ws_size;
    const float* input_states     = (const float*)d_in[0];
    const float* memory_states    = (const float*)d_in[1];
    const float* memory_weights   = (const float*)d_in[2];
    const int*   memory_masks     = (const int*)d_in[3];
    const float* attention_factors= (const float*)d_in[4];
    const int*   attention_masks  = (const int*)d_in[5];
    const float* Wq = (const float*)d_in[6];
    const float* bq = (const float*)d_in[7];
    const float* Wk = (const float*)d_in[8];
    const float* bk = (const float*)d_in[9];
    const float* Wv = (const float*)d_in[10];
    const float* bv = (const float*)d_in[11];
    const float* Wo = (const float*)d_in[12];
    const float* bo = (const float*)d_in[13];
    const float* g1 = (const float*)d_in[14];
    const float* b1 = (const float*)d_in[15];
    const float* We = (const float*)d_in[16];
    const float* be = (const float*)d_in[17];
    const float* Ws = (const float*)d_in[18];
    const float* bs = (const float*)d_in[19];
    const float* g2 = (const float*)d_in[20];
    const float* b2 = (const float*)d_in[21];

    float* out0 = (float*)d_out;                         // (4,1024,1024)
    float* attn = (float*)d_out + 4L * 1024 * 1024;      // (4,8,1024,1024)

    char* ws = (char*)d_ws;
    bf16_t* Wqb  = (bf16_t*)(ws + 0 * MB);
    bf16_t* Wkb  = (bf16_t*)(ws + 2 * MB);
    bf16_t* Wvb  = (bf16_t*)(ws + 4 * MB);
    bf16_t* Wob  = (bf16_t*)(ws + 6 * MB);
    bf16_t* Web  = (bf16_t*)(ws + 8 * MB);
    bf16_t* Wsb  = (bf16_t*)(ws + 12 * MB);
    bf16_t* inb  = (bf16_t*)(ws + 16 * MB);
    bf16_t* memb = (bf16_t*)(ws + 24 * MB);
    bf16_t* Qb   = (bf16_t*)(ws + 32 * MB);
    bf16_t* Kb   = (bf16_t*)(ws + 40 * MB);
    bf16_t* Vtb  = (bf16_t*)(ws + 48 * MB);
    bf16_t* hidb = (bf16_t*)(ws + 56 * MB);
    float*  preLN= (float*)(ws + 64 * MB);
    float*  out1f= (float*)(ws + 80 * MB);
    bf16_t* out1b= (bf16_t*)(ws + 96 * MB);
    bf16_t* hffn = (bf16_t*)(ws + 104 * MB);

    // all f32->bf16 casts in one launch (4M float4 total)
    cast8_kernel<<<16384, 256, 0, stream>>>(Wq, Wqb, Wk, Wkb, Wv, Wvb, Wo, Wob,
                                            We, Web, Ws, Wsb,
                                            input_states, inb, memory_states, memb);

    // Q = in @ Wq^T + bq (bf16 out), 64-row tiles
    gemm_bt<64,1,1,0,0,0><<<dim3(512, 1), 256, 0, stream>>>(
        inb, 1024, Wqb, 1024, bq, nullptr, 0, Qb, 1024, 1024, 8, 0,0,0,0,0, 1);
    // K = mem @ Wk^T + bk
    gemm_bt<64,1,1,0,0,0><<<dim3(512, 1), 256, 0, stream>>>(
        memb, 1024, Wkb, 1024, bk, nullptr, 0, Kb, 1024, 1024, 8, 0,0,0,0,0, 1);
    // V = mem @ Wv^T + bv, written transposed per head Vt[b,h,c,m]
    gemm_bt<64,1,1,0,0,1><<<dim3(512, 1), 256, 0, stream>>>(
        memb, 1024, Wvb, 1024, bv, nullptr, 0, Vtb, 1024, 1024, 8, 0,0,0,0,0, 1);
    // raw scores = Q_bh @ K_bh^T -> f32 into attn region
    gemm_bt<128,0,0,0,0,0><<<dim3(64, 32), 256, 0, stream>>>(
        Qb, 1024, Kb, 1024, nullptr, nullptr, 0, attn, 1024, 128, 8,
        1048576L, 128L, 1048576L, 128L, 1048576L, 8);
    // gate + softmax in place -> final probs
    gate_softmax_kernel<<<8192, 256, 0, stream>>>(attn, attention_factors,
                                                  memory_weights, memory_masks,
                                                  attention_masks);
    // hidden = P @ V
    pv_kernel<<<dim3(16, 32), 256, 0, stream>>>(attn, Vtb, hidb);
    // preLN1 = hidden @ Wo^T + bo + input_states
    gemm_bt<64,0,1,0,1,0><<<dim3(512, 1), 256, 0, stream>>>(
        hidb, 1024, Wob, 1024, bo, input_states, 1024, preLN, 1024, 1024, 8, 0,0,0,0,0, 1);
    // out1 = LN(preLN1) -> f32 + bf16
    ln_kernel<1><<<1024, 256, 0, stream>>>(preLN, g1, b1, out1f, out1b);
    // h = relu(out1 @ We^T + be) -> bf16 (4096,2048), 128-row tiles (512 blocks)
    gemm_bt<128,1,1,1,0,0><<<dim3(512, 1), 256, 0, stream>>>(
        out1b, 1024, Web, 1024, be, nullptr, 0, hffn, 2048, 1024, 16, 0,0,0,0,0, 1);
    // preLN2 = h @ Ws^T + bs + out1
    gemm_bt<64,0,1,0,1,0><<<dim3(512, 1), 256, 0, stream>>>(
        hffn, 2048, Wsb, 2048, bs, out1f, 1024, preLN, 1024, 2048, 8, 0,0,0,0,0, 1);
    // out = LN(preLN2) -> d_out chunk 0
    ln_kernel<0><<<1024, 256, 0, stream>>>(preLN, g2, b2, out0, nullptr);
}

// Round 13
// 318.008 us; speedup vs baseline: 1.0685x; 1.0685x over previous
//
#include <hip/hip_runtime.h>
#include <hip/hip_bf16.h>

typedef __bf16 bf16_t;
typedef __bf16 bf16x4 __attribute__((ext_vector_type(4)));
typedef __bf16 bf16x8 __attribute__((ext_vector_type(8)));
typedef float f32x4 __attribute__((ext_vector_type(4)));

typedef const __attribute__((address_space(1))) void gvoid_t;
typedef __attribute__((address_space(3))) void lvoid_t;

#define MB (1UL<<20)
#define NEGINF (-__builtin_inff())
#define SCALE 0.08838834764831845f

__device__ __forceinline__ void gload_lds16(const void* g, void* l) {
    __builtin_amdgcn_global_load_lds((gvoid_t*)g, (lvoid_t*)l, 16, 0, 0);
}

// bijective XCD swizzle for grids with nwg % 8 == 0 (T1, m204 form)
__device__ __forceinline__ int xcd_swizzle(int tile, int nwg) {
    const int cpx = nwg >> 3;
    return (tile & 7) * cpx + (tile >> 3);
}

// ---------------- merged cast f32 -> bf16: all 8 buffers in one launch --------
__global__ __launch_bounds__(256)
void cast8_kernel(const float* __restrict__ s0, bf16_t* __restrict__ d0,   // Wq 256K f4
                  const float* __restrict__ s1, bf16_t* __restrict__ d1,   // Wk
                  const float* __restrict__ s2, bf16_t* __restrict__ d2,   // Wv
                  const float* __restrict__ s3, bf16_t* __restrict__ d3,   // Wo
                  const float* __restrict__ s4, bf16_t* __restrict__ d4,   // We 512K
                  const float* __restrict__ s5, bf16_t* __restrict__ d5,   // Ws 512K
                  const float* __restrict__ s6, bf16_t* __restrict__ d6,   // in 1M
                  const float* __restrict__ s7, bf16_t* __restrict__ d7)   // mem 1M
{
    long i = (long)blockIdx.x * 256 + threadIdx.x;   // float4 index, total 4M
    const float* src; bf16_t* dst; long l;
    if      (i < 262144L)  { src = s0; dst = d0; l = i; }
    else if (i < 524288L)  { src = s1; dst = d1; l = i - 262144L; }
    else if (i < 786432L)  { src = s2; dst = d2; l = i - 524288L; }
    else if (i < 1048576L) { src = s3; dst = d3; l = i - 786432L; }
    else if (i < 1572864L) { src = s4; dst = d4; l = i - 1048576L; }
    else if (i < 2097152L) { src = s5; dst = d5; l = i - 1572864L; }
    else if (i < 3145728L) { src = s6; dst = d6; l = i - 2097152L; }
    else                   { src = s7; dst = d7; l = i - 3145728L; }
    float4 f = ((const float4*)src)[l];
    bf16x4 o;
    o[0] = (bf16_t)f.x; o[1] = (bf16_t)f.y; o[2] = (bf16_t)f.z; o[3] = (bf16_t)f.w;
    ((bf16x4*)dst)[l] = o;
}

// ---------------- generic BT GEMM: C[i,j] = sum_k A[i,k]*B[j,k] ----------------
// TM x 128 tile (TM=128: 4 waves 2x2 of 64x64; TM=64: 4 waves 1x4 of 64x32).
// BK=32, 2-phase LDS dbuf, COUNTED vmcnt + raw s_barrier (T4, R9-proven).
template<int TM, int OUT_BF16, int HAS_BIAS, int RELU, int HAS_RES, int VT_OUT>
__global__ __launch_bounds__(256)
void gemm_bt(const bf16_t* __restrict__ Ap, int lda,
             const bf16_t* __restrict__ Bp, int ldb,
             const float* __restrict__ bias,
             const float* __restrict__ res, int ldres,
             void* __restrict__ Cp, int ldc,
             int K, int tilesN,
             long aOffB, long aOffH, long bOffB, long bOffH, long cOffZ, int nH)
{
    __shared__ bf16_t sA[2 * TM * 32];
    __shared__ bf16_t sB[2 * 128 * 32];

    const int z = blockIdx.y;
    const int zb = z / nH, zh = z % nH;
    Ap += zb * aOffB + zh * aOffH;
    Bp += zb * bOffB + zh * bOffH;
    const long cOff = (long)z * cOffZ;

    const int tile = xcd_swizzle(blockIdx.x, gridDim.x);
    const int tm = tile / tilesN, tn = tile % tilesN;
    const int rowBase = tm * TM, colBase = tn * 128;
    const int t = threadIdx.x;
    const int wave = t >> 6, lane = t & 63;
    const int wr = (TM == 128) ? ((wave >> 1) * 64) : 0;
    const int wc = (TM == 128) ? ((wave & 1) * 64) : (wave * 32);
    constexpr int NF = (TM == 128) ? 4 : 2;

    f32x4 acc[4][NF] = {};

    const int e0 = t * 8;
    const int srow = e0 >> 5, scol = e0 & 31;

    auto stage = [&](int tt, int bi) {
        const int k0 = tt * 32;
        #pragma unroll
        for (int r = 0; r < TM / 64; ++r) {
            const int row = r * 64 + srow;
            gload_lds16(Ap + (long)(rowBase + row) * lda + k0 + scol,
                        (char*)sA + bi * (TM * 64) + r * 4096 + wave * 1024);
        }
        #pragma unroll
        for (int r = 0; r < 2; ++r) {
            const int row = r * 64 + srow;
            gload_lds16(Bp + (long)(colBase + row) * ldb + k0 + scol,
                        (char*)sB + bi * 8192 + r * 4096 + wave * 1024);
        }
    };

    const int nt = K >> 5;
    stage(0, 0);

    const int kf = (lane >> 4) * 8;
    const int lr = lane & 15;

    for (int tt = 0; tt < nt; ++tt) {
        const int cur = tt & 1;
        if (tt + 1 < nt) {
            stage(tt + 1, cur ^ 1);
            // wait for stage(tt) only; stage(tt+1) stays in flight (T4)
            if constexpr (TM == 128) {
                asm volatile("s_waitcnt vmcnt(4)" ::: "memory");
            } else {
                asm volatile("s_waitcnt vmcnt(3)" ::: "memory");
            }
        } else {
            asm volatile("s_waitcnt vmcnt(0)" ::: "memory");
        }
        __builtin_amdgcn_s_barrier();

        bf16x8 af[4], bfr[NF];
        #pragma unroll
        for (int m = 0; m < 4; ++m)
            af[m] = *(const bf16x8*)&sA[cur * (TM * 32) + (wr + m * 16 + lr) * 32 + kf];
        #pragma unroll
        for (int n = 0; n < NF; ++n)
            bfr[n] = *(const bf16x8*)&sB[cur * 4096 + (wc + n * 16 + lr) * 32 + kf];
        #pragma unroll
        for (int m = 0; m < 4; ++m)
            #pragma unroll
            for (int n = 0; n < NF; ++n)
                acc[m][n] = __builtin_amdgcn_mfma_f32_16x16x32_bf16(af[m], bfr[n], acc[m][n], 0, 0, 0);

        __builtin_amdgcn_s_barrier();
    }

    #pragma unroll
    for (int m = 0; m < 4; ++m) {
        #pragma unroll
        for (int r = 0; r < 4; ++r) {
            const int i = rowBase + wr + m * 16 + (lane >> 4) * 4 + r;
            #pragma unroll
            for (int n = 0; n < NF; ++n) {
                const int j = colBase + wc + n * 16 + (lane & 15);
                float v = acc[m][n][r];
                if constexpr (HAS_BIAS) v += bias[j];
                if constexpr (RELU) v = fmaxf(v, 0.0f);
                if constexpr (HAS_RES) v += res[(long)i * ldres + j];
                if constexpr (VT_OUT) {
                    const long o = (((long)(i >> 10) * 8 + (j >> 7)) * 128 + (j & 127)) * 1024 + (i & 1023);
                    ((bf16_t*)Cp)[o] = (bf16_t)v;
                } else if constexpr (OUT_BF16) {
                    ((bf16_t*)Cp)[cOff + (long)i * ldc + j] = (bf16_t)v;
                } else {
                    ((float*)Cp)[cOff + (long)i * ldc + j] = v;
                }
            }
        }
    }
}

// ---------------- fused QKV projection: one dispatch, blockIdx.y selects op ---
// y=0: Q = in@Wq^T+bq -> Qb ; y=1: K = mem@Wk^T+bk -> Kb ;
// y=2: V = mem@Wv^T+bv -> Vt[b,h,c,m] (transposed epilogue, block-uniform branch)
__global__ __launch_bounds__(256)
void qkv_gemm(const bf16_t* __restrict__ inb, const bf16_t* __restrict__ memb,
              const bf16_t* __restrict__ Wqb, const bf16_t* __restrict__ Wkb,
              const bf16_t* __restrict__ Wvb,
              const float* __restrict__ bq, const float* __restrict__ bk,
              const float* __restrict__ bv,
              bf16_t* __restrict__ Qb, bf16_t* __restrict__ Kb,
              bf16_t* __restrict__ Vtb)
{
    __shared__ bf16_t sA[2 * 64 * 32];
    __shared__ bf16_t sB[2 * 128 * 32];

    const int op = blockIdx.y;
    const bf16_t* Ap = (op == 0) ? inb : memb;
    const bf16_t* Bp = (op == 0) ? Wqb : (op == 1) ? Wkb : Wvb;
    const float* bias = (op == 0) ? bq : (op == 1) ? bk : bv;

    const int tile = xcd_swizzle(blockIdx.x, gridDim.x);
    const int tm = tile >> 3, tn = tile & 7;     // tilesN = 8
    const int rowBase = tm * 64, colBase = tn * 128;
    const int t = threadIdx.x;
    const int wave = t >> 6, lane = t & 63;
    const int wc = wave * 32;

    f32x4 acc[4][2] = {};

    const int e0 = t * 8;
    const int srow = e0 >> 5, scol = e0 & 31;

    auto stage = [&](int tt, int bi) {
        const int k0 = tt * 32;
        gload_lds16(Ap + (long)(rowBase + srow) * 1024 + k0 + scol,
                    (char*)sA + bi * 4096 + wave * 1024);
        #pragma unroll
        for (int r = 0; r < 2; ++r) {
            const int row = r * 64 + srow;
            gload_lds16(Bp + (long)(colBase + row) * 1024 + k0 + scol,
                        (char*)sB + bi * 8192 + r * 4096 + wave * 1024);
        }
    };

    stage(0, 0);

    const int kf = (lane >> 4) * 8;
    const int lr = lane & 15;

    for (int tt = 0; tt < 32; ++tt) {
        const int cur = tt & 1;
        if (tt + 1 < 32) {
            stage(tt + 1, cur ^ 1);
            asm volatile("s_waitcnt vmcnt(3)" ::: "memory");
        } else {
            asm volatile("s_waitcnt vmcnt(0)" ::: "memory");
        }
        __builtin_amdgcn_s_barrier();

        bf16x8 af[4], bfr[2];
        #pragma unroll
        for (int m = 0; m < 4; ++m)
            af[m] = *(const bf16x8*)&sA[cur * 2048 + (m * 16 + lr) * 32 + kf];
        #pragma unroll
        for (int n = 0; n < 2; ++n)
            bfr[n] = *(const bf16x8*)&sB[cur * 4096 + (wc + n * 16 + lr) * 32 + kf];
        #pragma unroll
        for (int m = 0; m < 4; ++m)
            #pragma unroll
            for (int n = 0; n < 2; ++n)
                acc[m][n] = __builtin_amdgcn_mfma_f32_16x16x32_bf16(af[m], bfr[n], acc[m][n], 0, 0, 0);

        __builtin_amdgcn_s_barrier();
    }

    bf16_t* Cp = (op == 0) ? Qb : (op == 1) ? Kb : Vtb;
    #pragma unroll
    for (int m = 0; m < 4; ++m) {
        #pragma unroll
        for (int r = 0; r < 4; ++r) {
            const int i = rowBase + m * 16 + (lane >> 4) * 4 + r;
            #pragma unroll
            for (int n = 0; n < 2; ++n) {
                const int j = colBase + wc + n * 16 + (lane & 15);   // GLOBAL column (R12 bug: colBase was missing)
                float v = acc[m][n][r] + bias[j];
                if (op == 2) {
                    // Vt[b][h][c][m]
                    const long o = (((long)(i >> 10) * 8 + (j >> 7)) * 128 + (j & 127)) * 1024 + (i & 1023);
                    Cp[o] = (bf16_t)v;
                } else {
                    Cp[(long)i * 1024 + j] = (bf16_t)v;
                }
            }
        }
    }
}

// ---------------- gate + softmax: raw scores -> FINAL probs in place ----------
__global__ __launch_bounds__(256)
void gate_softmax_kernel(float* __restrict__ Sio,           // (B,H,N,M) raw->probs
                         const float* __restrict__ factors, // (B,N,M)
                         const float* __restrict__ weights, // (B,M)
                         const int* __restrict__ mmask,     // (B,M)
                         const int* __restrict__ amask)     // (B,1,N,M)
{
    const int row = blockIdx.x * 4 + (threadIdx.x >> 6);
    const int lane = threadIdx.x & 63;
    const int n = row & 1023;
    const int b = row >> 13;
    float4* p = (float4*)(Sio + (long)row * 1024);
    const float4* fac = (const float4*)(factors + ((long)b * 1024 + n) * 1024);
    const float4* wt  = (const float4*)(weights + (long)b * 1024);
    const int4*   mm  = (const int4*)(mmask + (long)b * 1024);
    const int4*   am  = (const int4*)(amask + ((long)b * 1024 + n) * 1024);

    float vals[16];
    float mx = NEGINF;
    #pragma unroll
    for (int jj = 0; jj < 4; ++jj) {
        const int v4 = lane + jj * 64;
        float4 sc = p[v4];
        float4 fa = fac[v4];
        float4 w4 = wt[v4];
        int4 m4 = mm[v4];
        int4 a4 = am[v4];
        float4 g;
        g.x = (m4.x | a4.x) ? NEGINF : sc.x * SCALE * fa.x * w4.x;
        g.y = (m4.y | a4.y) ? NEGINF : sc.y * SCALE * fa.y * w4.y;
        g.z = (m4.z | a4.z) ? NEGINF : sc.z * SCALE * fa.z * w4.z;
        g.w = (m4.w | a4.w) ? NEGINF : sc.w * SCALE * fa.w * w4.w;
        vals[jj * 4 + 0] = g.x; vals[jj * 4 + 1] = g.y;
        vals[jj * 4 + 2] = g.z; vals[jj * 4 + 3] = g.w;
        mx = fmaxf(mx, fmaxf(fmaxf(g.x, g.y), fmaxf(g.z, g.w)));
    }
    #pragma unroll
    for (int off = 32; off > 0; off >>= 1) mx = fmaxf(mx, __shfl_xor(mx, off));
    float sum = 0.f;
    #pragma unroll
    for (int q = 0; q < 16; ++q) { float e = __expf(vals[q] - mx); vals[q] = e; sum += e; }
    #pragma unroll
    for (int off = 32; off > 0; off >>= 1) sum += __shfl_xor(sum, off);
    const float inv = 1.0f / sum;
    #pragma unroll
    for (int jj = 0; jj < 4; ++jj) {
        const int v4 = lane + jj * 64;
        float4 o;
        o.x = vals[jj * 4 + 0] * inv; o.y = vals[jj * 4 + 1] * inv;
        o.z = vals[jj * 4 + 2] * inv; o.w = vals[jj * 4 + 3] * inv;
        p[v4] = o;
    }
}

// ---------------- PV GEMM (64x128 tile, dbuf): hid = P @ Vt^T ----------------
// R9-proven form: conservative vmcnt(0)+__syncthreads (reg-staged A path).
__global__ __launch_bounds__(256)
void pv_kernel(const float* __restrict__ Sprob,       // (B,H,N,M) final probs
               const bf16_t* __restrict__ Vtb,        // [b][h][c][m]
               bf16_t* __restrict__ hidb)             // [b][n][h*128+c]
{
    __shared__ bf16_t sA[2 * 64 * 32];
    __shared__ bf16_t sB[2 * 128 * 32];

    const int bh = blockIdx.y;
    const int b = bh >> 3, h = bh & 7;
    const int rowBase = blockIdx.x * 64;
    const int t = threadIdx.x;
    const int wave = t >> 6, lane = t & 63;
    const int wc = wave * 32;

    const float* Sp = Sprob + (long)bh * 1048576;
    const bf16_t* Bp = Vtb + (long)bh * 131072;

    const int arow = rowBase + (t >> 2);
    const int acol = (t & 3) * 8;
    const float* Srow = Sp + (long)arow * 1024 + acol;

    f32x4 acc[4][2] = {};

    auto stageB = [&](int tt, int bi) {
        const int k0 = tt * 32;
        #pragma unroll
        for (int r = 0; r < 2; ++r) {
            const int row = r * 64 + ((t * 8) >> 5);
            gload_lds16(Bp + (long)row * 1024 + k0 + ((t * 8) & 31),
                        (char*)sB + bi * 8192 + r * 4096 + wave * 1024);
        }
    };

    auto procA = [&](int bi, float4 s0, float4 s1) {
        bf16x8 pb;
        pb[0] = (bf16_t)s0.x; pb[1] = (bf16_t)s0.y; pb[2] = (bf16_t)s0.z; pb[3] = (bf16_t)s0.w;
        pb[4] = (bf16_t)s1.x; pb[5] = (bf16_t)s1.y; pb[6] = (bf16_t)s1.z; pb[7] = (bf16_t)s1.w;
        *(bf16x8*)((char*)sA + bi * 4096 + t * 16) = pb;
    };

    stageB(0, 0);
    {
        float4 s0 = *(const float4*)Srow;
        float4 s1 = *(const float4*)(Srow + 4);
        procA(0, s0, s1);
    }
    asm volatile("s_waitcnt vmcnt(0)" ::: "memory");
    __syncthreads();

    const int kf = (lane >> 4) * 8;
    const int lr = lane & 15;

    for (int tt = 0; tt < 32; ++tt) {
        const int cur = tt & 1;
        float4 s0, s1;
        if (tt < 31) {
            stageB(tt + 1, cur ^ 1);
            s0 = *(const float4*)(Srow + (tt + 1) * 32);
            s1 = *(const float4*)(Srow + (tt + 1) * 32 + 4);
        }

        bf16x8 af[4], bfr[2];
        #pragma unroll
        for (int m = 0; m < 4; ++m)
            af[m] = *(const bf16x8*)&sA[cur * 2048 + (m * 16 + lr) * 32 + kf];
        #pragma unroll
        for (int n = 0; n < 2; ++n)
            bfr[n] = *(const bf16x8*)&sB[cur * 4096 + (wc + n * 16 + lr) * 32 + kf];
        #pragma unroll
        for (int m = 0; m < 4; ++m)
            #pragma unroll
            for (int n = 0; n < 2; ++n)
                acc[m][n] = __builtin_amdgcn_mfma_f32_16x16x32_bf16(af[m], bfr[n], acc[m][n], 0, 0, 0);

        if (tt < 31) procA(cur ^ 1, s0, s1);

        asm volatile("s_waitcnt vmcnt(0)" ::: "memory");
        __syncthreads();
    }

    #pragma unroll
    for (int m = 0; m < 4; ++m) {
        #pragma unroll
        for (int r = 0; r < 4; ++r) {
            const int i = rowBase + m * 16 + (lane >> 4) * 4 + r;
            #pragma unroll
            for (int n = 0; n < 2; ++n) {
                const int j = wc + n * 16 + (lane & 15);
                hidb[((long)b * 1024 + i) * 1024 + h * 128 + j] = (bf16_t)acc[m][n][r];
            }
        }
    }
}

// ---------------- LayerNorm over rows of 1024, one wave per row ----------------
template<int WRITE_BF16>
__global__ __launch_bounds__(256)
void ln_kernel(const float* __restrict__ x,
               const float* __restrict__ g,
               const float* __restrict__ bt,
               float* __restrict__ outf,
               bf16_t* __restrict__ outb)
{
    const int row = blockIdx.x * 4 + (threadIdx.x >> 6);
    const int lane = threadIdx.x & 63;
    const float* p = x + (long)row * 1024;
    float v[16];
    float s = 0.f;
    #pragma unroll
    for (int jj = 0; jj < 4; ++jj) {
        float4 f = ((const float4*)p)[lane + jj * 64];
        v[jj * 4 + 0] = f.x; v[jj * 4 + 1] = f.y; v[jj * 4 + 2] = f.z; v[jj * 4 + 3] = f.w;
        s += f.x + f.y + f.z + f.w;
    }
    #pragma unroll
    for (int off = 32; off > 0; off >>= 1) s += __shfl_xor(s, off);
    const float mu = s * (1.0f / 1024.0f);
    float q = 0.f;
    #pragma unroll
    for (int i = 0; i < 16; ++i) { float d = v[i] - mu; q += d * d; }
    #pragma unroll
    for (int off = 32; off > 0; off >>= 1) q += __shfl_xor(q, off);
    const float rstd = rsqrtf(q * (1.0f / 1024.0f) + 1e-5f);
    #pragma unroll
    for (int jj = 0; jj < 4; ++jj) {
        const int v4 = lane + jj * 64;
        float4 gg = ((const float4*)g)[v4];
        float4 bb = ((const float4*)bt)[v4];
        float4 o;
        o.x = (v[jj * 4 + 0] - mu) * rstd * gg.x + bb.x;
        o.y = (v[jj * 4 + 1] - mu) * rstd * gg.y + bb.y;
        o.z = (v[jj * 4 + 2] - mu) * rstd * gg.z + bb.z;
        o.w = (v[jj * 4 + 3] - mu) * rstd * gg.w + bb.w;
        ((float4*)outf)[(long)row * 256 + v4] = o;
        if constexpr (WRITE_BF16) {
            bf16x4 ob;
            ob[0] = (bf16_t)o.x; ob[1] = (bf16_t)o.y; ob[2] = (bf16_t)o.z; ob[3] = (bf16_t)o.w;
            ((bf16x4*)outb)[(long)row * 256 + v4] = ob;
        }
    }
}

extern "C" void kernel_launch(void* const* d_in, const int* in_sizes, int n_in,
                              void* d_out, int out_size, void* d_ws, size_t ws_size,
                              hipStream_t stream)
{
    (void)in_sizes; (void)n_in; (void)out_size; (void)ws_size;
    const float* input_states     = (const float*)d_in[0];
    const float* memory_states    = (const float*)d_in[1];
    const float* memory_weights   = (const float*)d_in[2];
    const int*   memory_masks     = (const int*)d_in[3];
    const float* attention_factors= (const float*)d_in[4];
    const int*   attention_masks  = (const int*)d_in[5];
    const float* Wq = (const float*)d_in[6];
    const float* bq = (const float*)d_in[7];
    const float* Wk = (const float*)d_in[8];
    const float* bk = (const float*)d_in[9];
    const float* Wv = (const float*)d_in[10];
    const float* bv = (const float*)d_in[11];
    const float* Wo = (const float*)d_in[12];
    const float* bo = (const float*)d_in[13];
    const float* g1 = (const float*)d_in[14];
    const float* b1 = (const float*)d_in[15];
    const float* We = (const float*)d_in[16];
    const float* be = (const float*)d_in[17];
    const float* Ws = (const float*)d_in[18];
    const float* bs = (const float*)d_in[19];
    const float* g2 = (const float*)d_in[20];
    const float* b2 = (const float*)d_in[21];

    float* out0 = (float*)d_out;                         // (4,1024,1024)
    float* attn = (float*)d_out + 4L * 1024 * 1024;      // (4,8,1024,1024)

    char* ws = (char*)d_ws;
    bf16_t* Wqb  = (bf16_t*)(ws + 0 * MB);
    bf16_t* Wkb  = (bf16_t*)(ws + 2 * MB);
    bf16_t* Wvb  = (bf16_t*)(ws + 4 * MB);
    bf16_t* Wob  = (bf16_t*)(ws + 6 * MB);
    bf16_t* Web  = (bf16_t*)(ws + 8 * MB);
    bf16_t* Wsb  = (bf16_t*)(ws + 12 * MB);
    bf16_t* inb  = (bf16_t*)(ws + 16 * MB);
    bf16_t* memb = (bf16_t*)(ws + 24 * MB);
    bf16_t* Qb   = (bf16_t*)(ws + 32 * MB);
    bf16_t* Kb   = (bf16_t*)(ws + 40 * MB);
    bf16_t* Vtb  = (bf16_t*)(ws + 48 * MB);
    bf16_t* hidb = (bf16_t*)(ws + 56 * MB);
    float*  preLN= (float*)(ws + 64 * MB);
    float*  out1f= (float*)(ws + 80 * MB);
    bf16_t* out1b= (bf16_t*)(ws + 96 * MB);
    bf16_t* hffn = (bf16_t*)(ws + 104 * MB);

    // all f32->bf16 casts in one launch (4M float4 total)
    cast8_kernel<<<16384, 256, 0, stream>>>(Wq, Wqb, Wk, Wkb, Wv, Wvb, Wo, Wob,
                                            We, Web, Ws, Wsb,
                                            input_states, inb, memory_states, memb);

    // Q,K,V projections in ONE dispatch (y selects op; V transposed epilogue)
    qkv_gemm<<<dim3(512, 3), 256, 0, stream>>>(inb, memb, Wqb, Wkb, Wvb,
                                               bq, bk, bv, Qb, Kb, Vtb);
    // raw scores = Q_bh @ K_bh^T -> f32 into attn region
    gemm_bt<128,0,0,0,0,0><<<dim3(64, 32), 256, 0, stream>>>(
        Qb, 1024, Kb, 1024, nullptr, nullptr, 0, attn, 1024, 128, 8,
        1048576L, 128L, 1048576L, 128L, 1048576L, 8);
    // gate + softmax in place -> final probs
    gate_softmax_kernel<<<8192, 256, 0, stream>>>(attn, attention_factors,
                                                  memory_weights, memory_masks,
                                                  attention_masks);
    // hidden = P @ V
    pv_kernel<<<dim3(16, 32), 256, 0, stream>>>(attn, Vtb, hidb);
    // preLN1 = hidden @ Wo^T + bo + input_states
    gemm_bt<64,0,1,0,1,0><<<dim3(512, 1), 256, 0, stream>>>(
        hidb, 1024, Wob, 1024, bo, input_states, 1024, preLN, 1024, 1024, 8, 0,0,0,0,0, 1);
    // out1 = LN(preLN1) -> f32 + bf16
    ln_kernel<1><<<1024, 256, 0, stream>>>(preLN, g1, b1, out1f, out1b);
    // h = relu(out1 @ We^T + be) -> bf16 (4096,2048), 128-row tiles
    gemm_bt<128,1,1,1,0,0><<<dim3(512, 1), 256, 0, stream>>>(
        out1b, 1024, Web, 1024, be, nullptr, 0, hffn, 2048, 1024, 16, 0,0,0,0,0, 1);
    // preLN2 = h @ Ws^T + bs + out1
    gemm_bt<64,0,1,0,1,0><<<dim3(512, 1), 256, 0, stream>>>(
        hffn, 2048, Wsb, 2048, bs, out1f, 1024, preLN, 1024, 2048, 8, 0,0,0,0,0, 1);
    // out = LN(preLN2) -> d_out chunk 0
    ln_kernel<0><<<1024, 256, 0, stream>>>(preLN, g2, b2, out0, nullptr);
}